// Round 19
// baseline (104.837 us; speedup 1.0000x reference)
//
#include <hip/hip_runtime.h>

#define LSEQ 8194
#define NPOS 2048

typedef _Float16 f16x8 __attribute__((ext_vector_type(8)));
typedef _Float16 f16x2 __attribute__((ext_vector_type(2)));
typedef __attribute__((ext_vector_type(4))) float f32x4;

static __device__ __forceinline__ float tanh_fast(float x){
    float p = __expf(2.0f * x);
    float r = __builtin_amdgcn_rcpf(1.0f + p);
    return 1.0f - 2.0f * r;
}
// sum 3 packed-f16x2 taps + relu (v_pk_add_f16 + v_pk_max_f16)
static __device__ __forceinline__ unsigned h3relu(unsigned a, unsigned b, unsigned c){
    union { f16x2 h; unsigned u; } x, y, z, r;
    x.u = a; y.u = b; z.u = c;
    f16x2 s = x.h + y.h + z.h;
    f16x2 zero = { (_Float16)0.0f, (_Float16)0.0f };
    r.h = __builtin_elementwise_max(s, zero);
    return r.u;
}
static __device__ __forceinline__ unsigned hpack(float a, float b){
    union { f16x2 h; unsigned u; } pk;
    pk.h = (f16x2){ (_Float16)a, (_Float16)b };
    return pk.u;
}

// K0: precompute shared tables once:
//  tblp: perm-layout tap table [3][26][20] u32 (f16x2), pos p=(cp&3)*4+(cp>>2)
//  wah : Wa as f16 row-major 128x128 (8192 u32 pairs)
__global__ __launch_bounds__(256) void k_tbl(
        const float* __restrict__ emb, const float* __restrict__ cw,
        const float* __restrict__ cb, const float* __restrict__ Wa,
        unsigned* __restrict__ tblp, unsigned* __restrict__ wah)
{
    int gid = blockIdx.x*256 + threadIdx.x;
    if (gid < 1248){
        int k = gid / 416;          // 416 = 26*16
        int rem = gid - k*416;
        int l = rem >> 4;
        int cp = rem & 15;
        int c0 = cp*2;
        float v0 = 0.f, v1 = 0.f;
        #pragma unroll
        for (int i = 0; i < 5; i++){
            float e = emb[l*5 + i];
            v0 += cw[(c0*5 + i)*3 + k] * e;
            v1 += cw[((c0+1)*5 + i)*3 + k] * e;
        }
        if (k == 2){ v0 += cb[c0]; v1 += cb[c0+1]; }
        tblp[k*520 + l*20 + (cp & 3)*4 + (cp >> 2)] = hpack(v0, v1);
    }
    for (int i = gid; i < 8192; i += 1280)
        wah[i] = hpack(Wa[2*i], Wa[2*i + 1]);
}

// K_FUSED (grid (16,128) = 2048 blocks, 128-n chunks, 2 sub-tiles):
// Per sub (2 barriers): gen V -> bshare (V dies) -> barrier -> MFMA with
// W-frags loaded TRANSIENTLY from global per sub (frees 24 persistent VGPRs:
// R10/R15/R17 register law -> now fits the (256,5) 102-VGPR cap) -> epar ->
// barrier -> per-wave register online-softmax -> pool from OWN bshare slots.
// 5 blocks/CU resident (LDS 26.8KB), 8 available -> +25% latency hiding.
// Writes part[(b*16+x)*128+d], stats[(b*16+x)*2] exactly once. No atomics.
__global__ __launch_bounds__(256, 5) void k_fused(
        const int* __restrict__ seq, const unsigned* __restrict__ tblp,
        const unsigned* __restrict__ wah, const float* __restrict__ va,
        float* __restrict__ part, float* __restrict__ stats)
{
    __shared__ __align__(16) unsigned tblH[1560];      // 6240 B perm table
    __shared__ unsigned short seqw16[4][132];          // pre-scaled offsets (x80)
    __shared__ uint4 bshare[16*64];                    // 16 KB f16 B-frags
    __shared__ float epar[4][64];
    __shared__ float red3[4][4][32];                   // [wave][q][a]

    int tid = threadIdx.x;
    int b   = blockIdx.y;
    int x   = blockIdx.x;
    int n0  = x * 128;

    for (int i = tid; i < 390; i += 256)
        ((uint4*)tblH)[i] = ((const uint4*)tblp)[i];
    const int* sb = seq + (size_t)b * LSEQ;
    for (int i = tid; i < 4*130; i += 256){
        int s = i / 130, off = i - s*130;
        seqw16[s][off] = (unsigned short)(sb[s*2048 + n0 + off] * 80);
    }

    int w = tid >> 6, lane = tid & 63;
    int m = lane & 15, q = lane >> 4;
    __syncthreads();

    const char* tb0 = (const char*)tblH + q*16;
    const char* tb1 = tb0 + 2080;
    const char* tb2 = tb1 + 2080;

    float accp[32];              // pooled (unnormalized, running-rescaled) partials
    #pragma unroll
    for (int j = 0; j < 32; j++) accp[j] = 0.f;
    float Mw = -3e38f, Sw = 0.f; // per-wave running softmax stats (identical
                                 // across waves: derived from the same epar)

    for (int sub = 0; sub < 2; sub++){
        int row = sub*64 + w*16 + m;
        {   // --- gen: V lives only inside this scope ---
            unsigned o0[4], o1[4], o2[4];
            #pragma unroll
            for (int s = 0; s < 4; s++){
                o0[s] = seqw16[s][row];
                o1[s] = seqw16[s][row+1];
                o2[s] = seqw16[s][row+2];
            }
            unsigned V[4][4];   // V[s][ki] = f16x2(chA,chB); cp=ki*4+q
            #pragma unroll
            for (int s = 0; s < 4; s++){
                uint4 t0 = *(const uint4*)(tb0 + o0[s]);
                uint4 t1 = *(const uint4*)(tb1 + o1[s]);
                uint4 t2 = *(const uint4*)(tb2 + o2[s]);
                V[s][0] = h3relu(t0.x, t1.x, t2.x);
                V[s][1] = h3relu(t0.y, t1.y, t2.y);
                V[s][2] = h3relu(t0.z, t1.z, t2.z);
                V[s][3] = h3relu(t0.w, t1.w, t2.w);
            }
            #pragma unroll
            for (int ki = 0; ki < 4; ki++){
                uint4 o;
                o.x = __builtin_amdgcn_perm(V[1][ki], V[0][ki], 0x05040100u);  // A_s0,A_s1
                o.y = __builtin_amdgcn_perm(V[3][ki], V[2][ki], 0x05040100u);  // A_s2,A_s3
                o.z = __builtin_amdgcn_perm(V[1][ki], V[0][ki], 0x07060302u);  // B_s0,B_s1
                o.w = __builtin_amdgcn_perm(V[3][ki], V[2][ki], 0x07060302u);  // B_s2,B_s3
                bshare[(w*4 + ki)*64 + lane] = o;
            }
        }
        __syncthreads();   // bshare ready

        // W_a A-frags loaded transiently per sub (L2-hot 32 KB; same total
        // load count as a block prologue would need at 2 subs)
        uint4 wfu[2][4];
        #pragma unroll
        for (int dtL = 0; dtL < 2; dtL++)
            #pragma unroll
            for (int ki = 0; ki < 4; ki++)
                wfu[dtL][ki] = *(const uint4*)((const char*)wah +
                    ((2*w+dtL)*16 + m)*256 + ki*64 + q*16);

        f32x4 acc[2][4];
        #pragma unroll
        for (int dtL = 0; dtL < 2; dtL++)
            #pragma unroll
            for (int rg = 0; rg < 4; rg++) acc[dtL][rg] = (f32x4){0.f,0.f,0.f,0.f};
        #pragma unroll
        for (int rg = 0; rg < 4; rg++){
            #pragma unroll
            for (int ki = 0; ki < 4; ki++){
                union { uint4 u; f16x8 f; } bu, a0, a1;
                bu.u = bshare[(rg*4 + ki)*64 + lane];
                a0.u = wfu[0][ki];
                a1.u = wfu[1][ki];
                acc[0][rg] = __builtin_amdgcn_mfma_f32_16x16x32_f16(a0.f, bu.f, acc[0][rg], 0, 0, 0);
                acc[1][rg] = __builtin_amdgcn_mfma_f32_16x16x32_f16(a1.f, bu.f, acc[1][rg], 0, 0, 0);
            }
        }
        // varg transient per sub (va is 512 B, L2/L1-hot)
        float4 vg0 = *(const float4*)&va[(2*w+0)*16 + q*4];
        float4 vg1 = *(const float4*)&va[(2*w+1)*16 + q*4];
        #pragma unroll
        for (int rg = 0; rg < 4; rg++){
            float ep = 0.f;
            ep += vg0.x * tanh_fast(acc[0][rg][0]);
            ep += vg0.y * tanh_fast(acc[0][rg][1]);
            ep += vg0.z * tanh_fast(acc[0][rg][2]);
            ep += vg0.w * tanh_fast(acc[0][rg][3]);
            ep += vg1.x * tanh_fast(acc[1][rg][0]);
            ep += vg1.y * tanh_fast(acc[1][rg][1]);
            ep += vg1.z * tanh_fast(acc[1][rg][2]);
            ep += vg1.w * tanh_fast(acc[1][rg][3]);
            ep += __shfl_xor(ep, 16);
            ep += __shfl_xor(ep, 32);
            if (lane < 16) epar[w][rg*16 + lane] = ep;
        }
        __syncthreads();   // epar ready (all MFMA bshare reads also done)

        // per-wave online softmax: lane's reference row = lane (0..63)
        float e4 = epar[0][lane] + epar[1][lane] + epar[2][lane] + epar[3][lane];
        float msub = e4;
        #pragma unroll
        for (int off = 32; off >= 1; off >>= 1)
            msub = fmaxf(msub, __shfl_xor(msub, off));
        float Mnew = fmaxf(Mw, msub);
        float alpha = __expf(Mw - Mnew);
        float wrl = __expf(e4 - Mnew);          // weight of row 'lane'
        float ssub = wrl;
        #pragma unroll
        for (int off = 32; off >= 1; off >>= 1) ssub += __shfl_xor(ssub, off);
        Sw = alpha * Sw + ssub;
        Mw = Mnew;
        float wr = __shfl(wrl, w*16 + m);       // weight of THIS thread's row

        // online pool update from this thread's OWN bshare slots
        #pragma unroll
        for (int ki = 0; ki < 4; ki++){
            uint4 o = bshare[(w*4 + ki)*64 + lane];
            union { f16x2 h; unsigned u; } uA01, uA23, uB01, uB23;
            uA01.u = o.x; uA23.u = o.y; uB01.u = o.z; uB23.u = o.w;
            accp[ki*8 + 0] = alpha * accp[ki*8 + 0] + wr * (float)uA01.h[0];
            accp[ki*8 + 1] = alpha * accp[ki*8 + 1] + wr * (float)uA01.h[1];
            accp[ki*8 + 2] = alpha * accp[ki*8 + 2] + wr * (float)uA23.h[0];
            accp[ki*8 + 3] = alpha * accp[ki*8 + 3] + wr * (float)uA23.h[1];
            accp[ki*8 + 4] = alpha * accp[ki*8 + 4] + wr * (float)uB01.h[0];
            accp[ki*8 + 5] = alpha * accp[ki*8 + 5] + wr * (float)uB01.h[1];
            accp[ki*8 + 6] = alpha * accp[ki*8 + 6] + wr * (float)uB23.h[0];
            accp[ki*8 + 7] = alpha * accp[ki*8 + 7] + wr * (float)uB23.h[1];
        }
    }

    // reduce accp over the 16 m-lanes sharing (w,q); rows differ per lane
    #pragma unroll
    for (int j = 0; j < 32; j++){
        accp[j] += __shfl_xor(accp[j], 1);
        accp[j] += __shfl_xor(accp[j], 2);
        accp[j] += __shfl_xor(accp[j], 4);
        accp[j] += __shfl_xor(accp[j], 8);
    }
    if (m == 0){
        #pragma unroll
        for (int j = 0; j < 32; j++) red3[w][q][j] = accp[j];
    }
    __syncthreads();
    if (tid < 128){
        // d = tid: ki=d>>5, q2=(d>>3)&3, par=(d>>2)&1, s=d&3
        // accp index a: chA(par=0) -> ki*8+s, chB(par=1) -> ki*8+4+s
        int ki = tid >> 5, q2 = (tid >> 3) & 3, par = (tid >> 2) & 1, s = tid & 3;
        int a = ki*8 + par*4 + s;
        part[((size_t)b*16 + x)*128 + tid] =
            red3[0][q2][a] + red3[1][q2][a] + red3[2][q2][a] + red3[3][q2][a];
    }
    if (tid == 0){
        stats[((size_t)b*16 + x)*2    ] = Mw;
        stats[((size_t)b*16 + x)*2 + 1] = Sw;
    }
}

// KB2: combine 16 chunk partials with online-softmax rescale.
// out[b][d] = sum_x part[b][x][d]*exp(m_x-M) / sum_x s_x*exp(m_x-M)
__global__ __launch_bounds__(128) void kb2_finish(const float* __restrict__ part,
        const float* __restrict__ stats, float* __restrict__ out)
{
    int b = blockIdx.x, d = threadIdx.x;
    const float* st = stats + (size_t)b*32;
    float M = -1e30f;
    #pragma unroll
    for (int x = 0; x < 16; x++) M = fmaxf(M, st[x*2]);
    float f[16], S = 0.f;
    #pragma unroll
    for (int x = 0; x < 16; x++){
        f[x] = __expf(st[x*2] - M);
        S += st[x*2+1] * f[x];
    }
    float inv = 1.0f / S;
    const float* p = part + (size_t)b*16*128 + d;
    float s = 0.f;
    #pragma unroll
    for (int x = 0; x < 16; x++) s += p[x*128] * f[x];
    out[b*128 + d] = s * inv;
}

extern "C" void kernel_launch(void* const* d_in, const int* in_sizes, int n_in,
                              void* d_out, int out_size, void* d_ws, size_t ws_size,
                              hipStream_t stream)
{
    const int*   seq = (const int*)d_in[0];
    const float* emb = (const float*)d_in[1];
    const float* cw  = (const float*)d_in[2];
    const float* cb  = (const float*)d_in[3];
    const float* Wa  = (const float*)d_in[4];
    const float* va  = (const float*)d_in[5];
    float* out = (float*)d_out;

    char* wsb = (char*)d_ws;
    float*    part  = (float*)wsb;                           // 1 MiB (128*16*128 f32)
    float*    stats = (float*)(wsb + (2<<20));               // 16 KiB (128*16*2 f32)
    unsigned* tblp  = (unsigned*)(wsb + (3<<20));            // 6240 B
    unsigned* wah   = (unsigned*)(wsb + (3<<20) + 16384);    // 32 KiB

    k_tbl     <<<5,            256, 0, stream>>>(emb, cw, cb, Wa, tblp, wah);
    k_fused   <<<dim3(16,128), 256, 0, stream>>>(seq, tblp, wah, va, part, stats);
    kb2_finish<<<128,          128, 0, stream>>>(part, stats, out);
}

// Round 20
// 97.851 us; speedup vs baseline: 1.0714x; 1.0714x over previous
//
#include <hip/hip_runtime.h>

#define LSEQ 8194
#define NPOS 2048

typedef _Float16 f16x8 __attribute__((ext_vector_type(8)));
typedef _Float16 f16x2 __attribute__((ext_vector_type(2)));
typedef __attribute__((ext_vector_type(4))) float f32x4;

static __device__ __forceinline__ float tanh_fast(float x){
    float p = __expf(2.0f * x);
    float r = __builtin_amdgcn_rcpf(1.0f + p);
    return 1.0f - 2.0f * r;
}
// sum 3 packed-f16x2 taps + relu (v_pk_add_f16 + v_pk_max_f16)
static __device__ __forceinline__ unsigned h3relu(unsigned a, unsigned b, unsigned c){
    union { f16x2 h; unsigned u; } x, y, z, r;
    x.u = a; y.u = b; z.u = c;
    f16x2 s = x.h + y.h + z.h;
    f16x2 zero = { (_Float16)0.0f, (_Float16)0.0f };
    r.h = __builtin_elementwise_max(s, zero);
    return r.u;
}
static __device__ __forceinline__ unsigned hpack(float a, float b){
    union { f16x2 h; unsigned u; } pk;
    pk.h = (f16x2){ (_Float16)a, (_Float16)b };
    return pk.u;
}

// K0: precompute shared tables once:
//  tblp: perm-layout tap table [3][26][20] u32 (f16x2), pos p=(cp&3)*4+(cp>>2)
//  wah : Wa as f16 row-major 128x128 (8192 u32 pairs)
__global__ __launch_bounds__(256) void k_tbl(
        const float* __restrict__ emb, const float* __restrict__ cw,
        const float* __restrict__ cb, const float* __restrict__ Wa,
        unsigned* __restrict__ tblp, unsigned* __restrict__ wah)
{
    int gid = blockIdx.x*256 + threadIdx.x;
    if (gid < 1248){
        int k = gid / 416;          // 416 = 26*16
        int rem = gid - k*416;
        int l = rem >> 4;
        int cp = rem & 15;
        int c0 = cp*2;
        float v0 = 0.f, v1 = 0.f;
        #pragma unroll
        for (int i = 0; i < 5; i++){
            float e = emb[l*5 + i];
            v0 += cw[(c0*5 + i)*3 + k] * e;
            v1 += cw[((c0+1)*5 + i)*3 + k] * e;
        }
        if (k == 2){ v0 += cb[c0]; v1 += cb[c0+1]; }
        tblp[k*520 + l*20 + (cp & 3)*4 + (cp >> 2)] = hpack(v0, v1);
    }
    for (int i = gid; i < 8192; i += 1280)
        wah[i] = hpack(Wa[2*i], Wa[2*i + 1]);
}

// K_FUSED (grid (8,128)): per (b, 256-n chunk), 4 sub-tiles of 64 rows.
// Per sub (2 barriers): gen V -> bshare (V dies: no spill) -> barrier ->
// MFMA -> epar -> barrier -> per-wave REGISTER online-softmax (all waves
// redundantly compute identical M/S from epar) -> pool update from this
// thread's OWN bshare slots.
// bounds (256,4): REGISTER LAW (R10/R15/R17 spilled when squeezed; R19's
// transient-W + 5-occupancy variant was latency-bound) — loop-carried set
// wfu(16)+accp(32)+acc(32)+misc needs the 128-VGPR cap at 4 blocks/CU.
// Writes part[(b*8+x)*128+d] and stats[(b*8+x)*2] exactly once. No atomics.
__global__ __launch_bounds__(256, 4) void k_fused(
        const int* __restrict__ seq, const unsigned* __restrict__ tblp,
        const unsigned* __restrict__ wah, const float* __restrict__ va,
        float* __restrict__ part, float* __restrict__ stats)
{
    __shared__ __align__(16) unsigned tblH[1560];      // 6240 B perm table
    __shared__ unsigned short seqw16[4][260];          // pre-scaled offsets (x80)
    __shared__ uint4 bshare[16*64];                    // 16 KB f16 B-frags
    __shared__ float epar[4][64];
    __shared__ float red3[4][4][32];                   // [wave][q][a]

    int tid = threadIdx.x;
    int b   = blockIdx.y;
    int x   = blockIdx.x;
    int n0  = x * 256;

    for (int i = tid; i < 390; i += 256)
        ((uint4*)tblH)[i] = ((const uint4*)tblp)[i];
    const int* sb = seq + (size_t)b * LSEQ;
    for (int i = tid; i < 4*258; i += 256){
        int s = i / 258, off = i - s*258;
        seqw16[s][off] = (unsigned short)(sb[s*2048 + n0 + off] * 80);
    }

    int w = tid >> 6, lane = tid & 63;
    int m = lane & 15, q = lane >> 4;

    // wave w's W_a A-frags (f16, pre-converted): 8 x b128 loads
    uint4 wfu[2][4];
    #pragma unroll
    for (int dtL = 0; dtL < 2; dtL++)
        #pragma unroll
        for (int ki = 0; ki < 4; ki++)
            wfu[dtL][ki] = *(const uint4*)((const char*)wah +
                ((2*w+dtL)*16 + m)*256 + ki*64 + q*16);
    float varg[2][4];
    #pragma unroll
    for (int dtL = 0; dtL < 2; dtL++)
        #pragma unroll
        for (int r = 0; r < 4; r++)
            varg[dtL][r] = va[(2*w+dtL)*16 + q*4 + r];
    __syncthreads();

    const char* tb0 = (const char*)tblH + q*16;
    const char* tb1 = tb0 + 2080;
    const char* tb2 = tb1 + 2080;

    float accp[32];              // pooled (unnormalized, running-rescaled) partials
    #pragma unroll
    for (int j = 0; j < 32; j++) accp[j] = 0.f;
    float Mw = -3e38f, Sw = 0.f; // per-wave running softmax stats (identical
                                 // across waves: derived from the same epar)

    for (int sub = 0; sub < 4; sub++){
        int row = sub*64 + w*16 + m;
        {   // --- gen: V lives only inside this scope (dies before MFMA) ---
            unsigned o0[4], o1[4], o2[4];
            #pragma unroll
            for (int s = 0; s < 4; s++){
                o0[s] = seqw16[s][row];
                o1[s] = seqw16[s][row+1];
                o2[s] = seqw16[s][row+2];
            }
            unsigned V[4][4];   // V[s][ki] = f16x2(chA,chB); cp=ki*4+q
            #pragma unroll
            for (int s = 0; s < 4; s++){
                uint4 t0 = *(const uint4*)(tb0 + o0[s]);
                uint4 t1 = *(const uint4*)(tb1 + o1[s]);
                uint4 t2 = *(const uint4*)(tb2 + o2[s]);
                V[s][0] = h3relu(t0.x, t1.x, t2.x);
                V[s][1] = h3relu(t0.y, t1.y, t2.y);
                V[s][2] = h3relu(t0.z, t1.z, t2.z);
                V[s][3] = h3relu(t0.w, t1.w, t2.w);
            }
            #pragma unroll
            for (int ki = 0; ki < 4; ki++){
                uint4 o;
                o.x = __builtin_amdgcn_perm(V[1][ki], V[0][ki], 0x05040100u);  // A_s0,A_s1
                o.y = __builtin_amdgcn_perm(V[3][ki], V[2][ki], 0x05040100u);  // A_s2,A_s3
                o.z = __builtin_amdgcn_perm(V[1][ki], V[0][ki], 0x07060302u);  // B_s0,B_s1
                o.w = __builtin_amdgcn_perm(V[3][ki], V[2][ki], 0x07060302u);  // B_s2,B_s3
                bshare[(w*4 + ki)*64 + lane] = o;
            }
        }
        __syncthreads();   // bshare ready

        f32x4 acc[2][4];
        #pragma unroll
        for (int dtL = 0; dtL < 2; dtL++)
            #pragma unroll
            for (int rg = 0; rg < 4; rg++) acc[dtL][rg] = (f32x4){0.f,0.f,0.f,0.f};
        #pragma unroll
        for (int rg = 0; rg < 4; rg++){
            #pragma unroll
            for (int ki = 0; ki < 4; ki++){
                union { uint4 u; f16x8 f; } bu, a0, a1;
                bu.u = bshare[(rg*4 + ki)*64 + lane];
                a0.u = wfu[0][ki];
                a1.u = wfu[1][ki];
                acc[0][rg] = __builtin_amdgcn_mfma_f32_16x16x32_f16(a0.f, bu.f, acc[0][rg], 0, 0, 0);
                acc[1][rg] = __builtin_amdgcn_mfma_f32_16x16x32_f16(a1.f, bu.f, acc[1][rg], 0, 0, 0);
            }
        }
        #pragma unroll
        for (int rg = 0; rg < 4; rg++){
            float ep = 0.f;
            #pragma unroll
            for (int dtL = 0; dtL < 2; dtL++){
                ep += varg[dtL][0] * tanh_fast(acc[dtL][rg][0]);
                ep += varg[dtL][1] * tanh_fast(acc[dtL][rg][1]);
                ep += varg[dtL][2] * tanh_fast(acc[dtL][rg][2]);
                ep += varg[dtL][3] * tanh_fast(acc[dtL][rg][3]);
            }
            ep += __shfl_xor(ep, 16);
            ep += __shfl_xor(ep, 32);
            if (lane < 16) epar[w][rg*16 + lane] = ep;
        }
        __syncthreads();   // epar ready (all MFMA bshare reads also done)

        // per-wave online softmax: lane's reference row = lane (0..63)
        float e4 = epar[0][lane] + epar[1][lane] + epar[2][lane] + epar[3][lane];
        float msub = e4;
        #pragma unroll
        for (int off = 32; off >= 1; off >>= 1)
            msub = fmaxf(msub, __shfl_xor(msub, off));
        float Mnew = fmaxf(Mw, msub);
        float alpha = __expf(Mw - Mnew);
        float wrl = __expf(e4 - Mnew);          // weight of row 'lane'
        float ssub = wrl;
        #pragma unroll
        for (int off = 32; off >= 1; off >>= 1) ssub += __shfl_xor(ssub, off);
        Sw = alpha * Sw + ssub;
        Mw = Mnew;
        float wr = __shfl(wrl, w*16 + m);       // weight of THIS thread's row

        // online pool update from this thread's OWN bshare slots
        // (it wrote them this sub; overwrites them next sub: thread-local order)
        #pragma unroll
        for (int ki = 0; ki < 4; ki++){
            uint4 o = bshare[(w*4 + ki)*64 + lane];
            union { f16x2 h; unsigned u; } uA01, uA23, uB01, uB23;
            uA01.u = o.x; uA23.u = o.y; uB01.u = o.z; uB23.u = o.w;
            accp[ki*8 + 0] = alpha * accp[ki*8 + 0] + wr * (float)uA01.h[0];
            accp[ki*8 + 1] = alpha * accp[ki*8 + 1] + wr * (float)uA01.h[1];
            accp[ki*8 + 2] = alpha * accp[ki*8 + 2] + wr * (float)uA23.h[0];
            accp[ki*8 + 3] = alpha * accp[ki*8 + 3] + wr * (float)uA23.h[1];
            accp[ki*8 + 4] = alpha * accp[ki*8 + 4] + wr * (float)uB01.h[0];
            accp[ki*8 + 5] = alpha * accp[ki*8 + 5] + wr * (float)uB01.h[1];
            accp[ki*8 + 6] = alpha * accp[ki*8 + 6] + wr * (float)uB23.h[0];
            accp[ki*8 + 7] = alpha * accp[ki*8 + 7] + wr * (float)uB23.h[1];
        }
    }

    // reduce accp over the 16 m-lanes sharing (w,q); rows differ per lane
    #pragma unroll
    for (int j = 0; j < 32; j++){
        accp[j] += __shfl_xor(accp[j], 1);
        accp[j] += __shfl_xor(accp[j], 2);
        accp[j] += __shfl_xor(accp[j], 4);
        accp[j] += __shfl_xor(accp[j], 8);
    }
    if (m == 0){
        #pragma unroll
        for (int j = 0; j < 32; j++) red3[w][q][j] = accp[j];
    }
    __syncthreads();
    if (tid < 128){
        // d = tid: ki=d>>5, q2=(d>>3)&3, par=(d>>2)&1, s=d&3
        // accp index a: chA(par=0) -> ki*8+s, chB(par=1) -> ki*8+4+s
        int ki = tid >> 5, q2 = (tid >> 3) & 3, par = (tid >> 2) & 1, s = tid & 3;
        int a = ki*8 + par*4 + s;
        part[((size_t)b*8 + x)*128 + tid] =
            red3[0][q2][a] + red3[1][q2][a] + red3[2][q2][a] + red3[3][q2][a];
    }
    if (tid == 0){
        stats[((size_t)b*8 + x)*2    ] = Mw;
        stats[((size_t)b*8 + x)*2 + 1] = Sw;
    }
}

// KB2: combine chunk partials with online-softmax rescale.
// out[b][d] = sum_x part[b][x][d]*exp(m_x-M) / sum_x s_x*exp(m_x-M)
__global__ __launch_bounds__(128) void kb2_finish(const float* __restrict__ part,
        const float* __restrict__ stats, float* __restrict__ out)
{
    int b = blockIdx.x, d = threadIdx.x;
    const float* st = stats + (size_t)b*16;
    float M = -1e30f;
    #pragma unroll
    for (int x = 0; x < 8; x++) M = fmaxf(M, st[x*2]);
    float f[8], S = 0.f;
    #pragma unroll
    for (int x = 0; x < 8; x++){
        f[x] = __expf(st[x*2] - M);
        S += st[x*2+1] * f[x];
    }
    float inv = 1.0f / S;
    const float* p = part + (size_t)b*8*128 + d;
    float s = 0.f;
    #pragma unroll
    for (int x = 0; x < 8; x++) s += p[x*128] * f[x];
    out[b*128 + d] = s * inv;
}

extern "C" void kernel_launch(void* const* d_in, const int* in_sizes, int n_in,
                              void* d_out, int out_size, void* d_ws, size_t ws_size,
                              hipStream_t stream)
{
    const int*   seq = (const int*)d_in[0];
    const float* emb = (const float*)d_in[1];
    const float* cw  = (const float*)d_in[2];
    const float* cb  = (const float*)d_in[3];
    const float* Wa  = (const float*)d_in[4];
    const float* va  = (const float*)d_in[5];
    float* out = (float*)d_out;

    char* wsb = (char*)d_ws;
    float*    part  = (float*)wsb;                           // 512 KiB (128*8*128 f32)
    float*    stats = (float*)(wsb + (1<<20));               // 8 KiB (128*8*2 f32)
    unsigned* tblp  = (unsigned*)(wsb + (2<<20));            // 6240 B
    unsigned* wah   = (unsigned*)(wsb + (2<<20) + 16384);    // 32 KiB

    k_tbl     <<<5,           256, 0, stream>>>(emb, cw, cb, Wa, tblp, wah);
    k_fused   <<<dim3(8,128), 256, 0, stream>>>(seq, tblp, wah, va, part, stats);
    kb2_finish<<<128,         128, 0, stream>>>(part, stats, out);
}